// Round 13
// baseline (230.713 us; speedup 1.0000x reference)
//
#include <hip/hip_runtime.h>
#include <hip/hip_bf16.h>

typedef __bf16 bf16;
typedef __bf16 bf16x8 __attribute__((ext_vector_type(8)));
typedef __bf16 bf16x4 __attribute__((ext_vector_type(4)));
typedef float f32x4 __attribute__((ext_vector_type(4)));
typedef float f32x16 __attribute__((ext_vector_type(16)));
typedef unsigned int uint;

#define NB 4
#define NS 2048
#define ND 1024
#define NHH 16
#define NHD 64

__device__ __forceinline__ void gload_lds16(const void* g, void* l) {
  __builtin_amdgcn_global_load_lds((const __attribute__((address_space(1))) void*)g,
                                   (__attribute__((address_space(3))) void*)l, 16, 0, 0);
}

__device__ __forceinline__ f32x4 mfma16(bf16x8 a, bf16x8 b, f32x4 c) {
  return __builtin_amdgcn_mfma_f32_16x16x32_bf16(a, b, c, 0, 0, 0);
}
__device__ __forceinline__ f32x16 mfma32(bf16x8 a, bf16x8 b, f32x16 c) {
  return __builtin_amdgcn_mfma_f32_32x32x16_bf16(a, b, c, 0, 0, 0);
}
__device__ __forceinline__ uint cvtpk(float lo, float hi) {
  uint r;
  asm("v_cvt_pk_bf16_f32 %0, %1, %2" : "=v"(r) : "v"(lo), "v"(hi));
  return r;
}
__device__ __forceinline__ void swap32u(uint& a, uint& b) {
  asm("v_permlane32_swap_b32 %0, %1" : "+v"(a), "+v"(b));
}
__device__ __forceinline__ float expv(float x) {
  float r;
  asm("v_exp_f32 %0, %1" : "=v"(r) : "v"(x));
  return r;
}
#define BARRIER()                          \
  do {                                     \
    asm volatile("" ::: "memory");         \
    __builtin_amdgcn_s_barrier();          \
    asm volatile("" ::: "memory");         \
  } while (0)
#define LGKM_DRAIN() asm volatile("s_waitcnt lgkmcnt(0)" ::: "memory")
#define VM_DRAIN() asm volatile("s_waitcnt vmcnt(0)" ::: "memory")

// --- fused prep: 4 weights->bf16 | mask->bias | mask->packed clean bits ---
__global__ __launch_bounds__(256) void prep(
    const float4* __restrict__ w0, const float4* __restrict__ w1,
    const float4* __restrict__ w2, const float4* __restrict__ w3,
    bf16x4* __restrict__ wout, float scale0, int n4each,
    const int* __restrict__ m, float* __restrict__ mb,
    uint* __restrict__ cleanw, int nmask) {
  const int bid = blockIdx.x;
  if (bid < 4096) {
    int i = bid * 256 + threadIdx.x;
    int w = i / n4each;
    int j = i - w * n4each;
    const float4* src = (w == 0) ? w0 : (w == 1) ? w1 : (w == 2) ? w2 : w3;
    float sc = (w == 0) ? scale0 : 1.0f;
    float4 v = src[j];
    bf16x4 o;
    o[0] = (bf16)(v.x * sc);
    o[1] = (bf16)(v.y * sc);
    o[2] = (bf16)(v.z * sc);
    o[3] = (bf16)(v.w * sc);
    wout[i] = o;
  } else if (bid < 4128) {
    int i = (bid - 4096) * 256 + threadIdx.x;
    if (i < nmask) mb[i] = m[i] ? 0.0f : -3e38f;
  } else {
    int i = threadIdx.x;
    if (i < 128) {
      const int* p = m + i * 64;
      int all1 = 1;
#pragma unroll
      for (int j = 0; j < 64; j += 4) {
        int4 v = *(const int4*)(p + j);
        all1 &= (v.x && v.y && v.z && v.w) ? 1 : 0;
      }
      unsigned long long bal = __ballot(all1);
      int wv = i >> 6, lane = i & 63;
      if (lane == 0) {
        cleanw[2 * wv] = (uint)bal;
        cleanw[2 * wv + 1] = (uint)(bal >> 32);
      }
    }
  }
}

// ---- z-fused projection GEMM: {Q,K,V} = f32-A @ W^T ----
// Tile 128x128, 4 waves, wave-tile 32(M)x128(N), acc[2][8].
// A: NO LDS -- per-lane direct f32 fragment loads (2 x float4 per frag, rows
//    unique per wave), cvt -> bf16 in-register. Depth-1 prefetch.
// B: only LDS user. 8KB ping-pong via gload_lds (2/thread); source slots
//    pre-swizzled (slot ^= (lane>>3)&3) so swizzled ds_read_b128
//    (g ^= (r>>1)&3) is 2-way bank-conflict-free (T21 both-sides rule).
// Sync: one {lgkm-drain; vmcnt(0); barrier} per iter -- loads are one full
// iteration old at the wait. Ping-pong safety: reads of buf b (iter t)
// retire at t+1's drain+barrier BEFORE t+1's gload writes b.
// grid 1536 (= 3z x 64 rowtiles x 8 coltiles), XCD-chunked; z==2 writes V
// transposed to Vt[bh][d][s].
__global__ __launch_bounds__(256) void proj_gemm(
    const float* __restrict__ Aq, const float* __restrict__ Ak,
    const float* __restrict__ Av, const bf16* __restrict__ Wb,
    bf16* __restrict__ Qb, bf16* __restrict__ Kb, bf16* __restrict__ Vtb) {
  __shared__ bf16 Bs[2][4096];  // [128 rows][4 slots x 8 bf16], slot-swizzled
  const int tid = threadIdx.x;
  const int lane = tid & 63, wv = tid >> 6;
  const int r = lane & 15, g = lane >> 4;
  const int bid = blockIdx.x;
  const int wg = (bid & 7) * 192 + (bid >> 3);  // 1536 = 8*192, bijective
  const int z = wg >> 9;
  const int t5 = wg & 511;
  const int rowTile = t5 >> 3;          // 0..63 (within z)
  const int colBase = (t5 & 7) * 128;

  const float* A = (z == 0) ? Aq : (z == 1) ? Ak : Av;
  const bf16* Bw = Wb + (long)z * ND * ND;

  // A fragment bases: frag m covers rows wv*32 + m*16 + r
  const float* aBase0 = A + (long)(rowTile * 128 + wv * 32 + r) * ND + 8 * g;
  const float* aBase1 = aBase0 + 16L * ND;

  // B staging: thread covers LDS rows brow, brow+64; slot pre-swizzle
  const int brow = wv * 16 + (lane >> 2);
  const int bslot = (lane & 3) ^ ((lane >> 3) & 3);
  const bf16* bsrc0 = Bw + (long)(colBase + brow) * ND + 8 * bslot;
  const bf16* bsrc1 = Bw + (long)(colBase + brow + 64) * ND + 8 * bslot;
  bf16* BsE = &Bs[0][0];

  // read offset: row2 = n*16 + r, swizzled slot g' = g ^ ((r>>1)&3)
  const int rdoff = r * 64 + ((g ^ ((r >> 1) & 3)) << 4);

  f32x4 acc[2][8] = {};

  float4 a0 = *(const float4*)(aBase0);
  float4 a1 = *(const float4*)(aBase0 + 4);
  float4 a2 = *(const float4*)(aBase1);
  float4 a3 = *(const float4*)(aBase1 + 4);
  gload_lds16(bsrc0, BsE + wv * 512);
  gload_lds16(bsrc1, BsE + 2048 + wv * 512);

  for (int t = 0; t < 32; t++) {
    LGKM_DRAIN();  // reads of t-1 retired -> buf (t+1)&1 free for overwrite
    VM_DRAIN();    // own gloads/loads of tile t (issued at t-1) landed
    BARRIER();     // all waves' tile-t B in LDS; all waves' old reads done

    // cvt A(t) -> bf16 fragments (reads OLD a0..a3 values; SSA-safe)
    bf16x8 af0, af1;
    af0[0] = (bf16)a0.x; af0[1] = (bf16)a0.y;
    af0[2] = (bf16)a0.z; af0[3] = (bf16)a0.w;
    af0[4] = (bf16)a1.x; af0[5] = (bf16)a1.y;
    af0[6] = (bf16)a1.z; af0[7] = (bf16)a1.w;
    af1[0] = (bf16)a2.x; af1[1] = (bf16)a2.y;
    af1[2] = (bf16)a2.z; af1[3] = (bf16)a2.w;
    af1[4] = (bf16)a3.x; af1[5] = (bf16)a3.y;
    af1[6] = (bf16)a3.z; af1[7] = (bf16)a3.w;

    if (t + 1 < 32) {  // issue tile t+1 (lands by t+1's VM_DRAIN)
      const int k1 = (t + 1) * 32;
      const int nb = (t + 1) & 1;
      gload_lds16(bsrc0 + k1, BsE + nb * 4096 + wv * 512);
      gload_lds16(bsrc1 + k1, BsE + nb * 4096 + 2048 + wv * 512);
      a0 = *(const float4*)(aBase0 + k1);
      a1 = *(const float4*)(aBase0 + k1 + 4);
      a2 = *(const float4*)(aBase1 + k1);
      a3 = *(const float4*)(aBase1 + k1 + 4);
    }

    const char* Bp = (const char*)BsE + (t & 1) * 8192 + rdoff;
#pragma unroll
    for (int n = 0; n < 8; n++) {
      bf16x8 bfr = *(const bf16x8*)(Bp + n * 1024);
      acc[0][n] = mfma16(af0, bfr, acc[0][n]);
      acc[1][n] = mfma16(af1, bfr, acc[1][n]);
    }
  }

  if (z <= 1) {
    bf16* C = z ? Kb : Qb;
#pragma unroll
    for (int m = 0; m < 2; m++)
#pragma unroll
      for (int n = 0; n < 8; n++)
#pragma unroll
        for (int q = 0; q < 4; q++) {
          int row = rowTile * 128 + wv * 32 + m * 16 + 4 * g + q;
          int col = colBase + n * 16 + r;
          C[(long)row * ND + col] = (bf16)acc[m][n][q];
        }
  } else {
    const int rw = rowTile * 128;
    const int b = rw >> 11;
    const int sbase = (rw & 2047) + wv * 32;
#pragma unroll
    for (int m = 0; m < 2; m++) {
#pragma unroll
      for (int n = 0; n < 8; n++) {
        int col = colBase + n * 16 + r;
        int h = col >> 6, d = col & 63;
        int s = sbase + m * 16 + 4 * g;
        bf16x4 pk;
#pragma unroll
        for (int q = 0; q < 4; q++) pk[q] = (bf16)acc[m][n][q];
        *(bf16x4*)(Vtb + ((long)(b * NHH + h) * NHD + d) * NS + s) = pk;
      }
    }
  }
}

// ----- 128x64 bf16 GEMM, C = A @ B^T + bias, erf-GELU, f32 out ----------
__global__ __launch_bounds__(256) void gemm_out(
    const bf16* __restrict__ A, const bf16* __restrict__ Bw,
    float* __restrict__ Cf, const float* __restrict__ bias, int M, int N, int K) {
  __shared__ bf16 As[2][128 * 32];
  __shared__ bf16 Bs[2][64 * 32];
  bf16* As0 = &As[0][0];
  bf16* Bs0 = &Bs[0][0];
  const int tid = threadIdx.x;
  const int lane = tid & 63, wv = tid >> 6;
  const int wr = wv >> 1, wc = wv & 1;
  const int g = lane >> 4, r = lane & 15;
  const int nx = N >> 6;
  const int chunk = gridDim.x >> 3;
  const int bid = blockIdx.x;
  const int wg = (bid & 7) * chunk + (bid >> 3);
  const int colBase = (wg % nx) * 64;
  const int rowBase = (wg / nx) * 128;

  const int sR = lane >> 2;
  const int sC = (lane & 3) * 8;
  const bf16* aj0 = A + (long)(rowBase + wv * 32 + sR) * K + sC;
  const bf16* aj1 = A + (long)(rowBase + wv * 32 + 16 + sR) * K + sC;
  const bf16* bj = Bw + (long)(colBase + wv * 16 + sR) * K + sC;

#define GSTAGE(bi, kk)                                          \
  do {                                                          \
    gload_lds16(aj0 + (kk), As0 + (bi) * 4096 + wv * 1024);     \
    gload_lds16(aj1 + (kk), As0 + (bi) * 4096 + wv * 1024 + 512); \
    gload_lds16(bj + (kk), Bs0 + (bi) * 2048 + wv * 512);       \
  } while (0)

  f32x4 acc[4][2] = {};

  GSTAGE(0, 0);
  int cur = 0;
  for (int k0 = 0; k0 < K; k0 += 32) {
    LGKM_DRAIN();
    BARRIER();
    if (k0 + 32 < K) {
      GSTAGE(cur ^ 1, k0 + 32);
      asm volatile("s_waitcnt vmcnt(3)" ::: "memory");
    } else {
      VM_DRAIN();
    }
    BARRIER();
    __builtin_amdgcn_sched_barrier(0);
    const bf16* Ac = As0 + cur * 4096;
    const bf16* Bc = Bs0 + cur * 2048;
    bf16x8 af[4], bfr[2];
#pragma unroll
    for (int m = 0; m < 4; m++)
      af[m] = *(const bf16x8*)(Ac + (wr * 64 + m * 16 + r) * 32 + g * 8);
#pragma unroll
    for (int n = 0; n < 2; n++)
      bfr[n] = *(const bf16x8*)(Bc + (wc * 32 + n * 16 + r) * 32 + g * 8);
    __builtin_amdgcn_s_setprio(1);
#pragma unroll
    for (int m = 0; m < 4; m++)
#pragma unroll
      for (int n = 0; n < 2; n++)
        acc[m][n] = mfma16(af[m], bfr[n], acc[m][n]);
    __builtin_amdgcn_s_setprio(0);
    cur ^= 1;
  }
#undef GSTAGE

#pragma unroll
  for (int m = 0; m < 4; m++)
#pragma unroll
    for (int n = 0; n < 2; n++)
#pragma unroll
      for (int q = 0; q < 4; q++) {
        int row = rowBase + wr * 64 + m * 16 + 4 * g + q;
        int col = colBase + wc * 32 + n * 16 + r;
        float v = acc[m][n][q] + bias[col];
        v = 0.5f * v * (1.0f + erff(v * 0.70710678118654752f));
        Cf[(long)row * N + col] = v;
      }
}

// ------- flash attention: 8-wave, swapped-operand, shift-free softmax ----
// QBLK=256 (8 waves x 32 q-rows), KBLK=64. 3-buffer/1-barrier counted-vmcnt
// pipeline (distance-2 buffer reuse). 1 K-load + 1 V-load per wave per tile
// -> vmcnt(2). grid 512, XCD-swizzled. Logits base-2: p = 2^st.
__global__ __launch_bounds__(512) void attn_fwd4(
    const bf16* __restrict__ Q, const bf16* __restrict__ K,
    const bf16* __restrict__ Vt, const float* __restrict__ mbias,
    const uint* __restrict__ cleanw, bf16* __restrict__ ctx) {
  __shared__ bf16 Ks[3][64 * 64];
  __shared__ bf16 Vs[3][64 * 64];
  bf16* Ks0 = &Ks[0][0];
  bf16* Vs0 = &Vs[0][0];
  const int tid = threadIdx.x;
  const int lane = tid & 63, wv = tid >> 6;
  const int ql = lane & 31, hi = lane >> 5;
  const int g = blockIdx.x;
  const int gx = (g & 63) >> 3;
  const int bh = ((g >> 6) << 3) | (g & 7);
  const int b = bh >> 4, h = bh & 15;
  const int q0 = gx * 256 + wv * 32;

  const bf16* Qp = Q + ((long)(b * NS + q0 + ql)) * ND + h * NHD;
  const bf16* Kp = K + ((long)b * NS) * ND + h * NHD;
  const bf16* Vp = Vt + (long)bh * NHD * NS;
  const float* mbp = mbias + b * NS;
  const uint cw = cleanw[b];

  bf16x8 qf[4];
#pragma unroll
  for (int cd = 0; cd < 4; cd++)
    qf[cd] = *(const bf16x8*)(Qp + cd * 16 + hi * 8);

  f32x16 o[2] = {};
  float lrun = 0.f;

  const int Lrow = wv * 8 + (lane >> 3);
  const int scb = ((lane & 7) * 16) ^ ((Lrow & 7) << 4);
  const bf16* kS = Kp + (long)Lrow * ND + (scb >> 1);
  const bf16* vS = Vp + (long)Lrow * NS + (scb >> 1);

#define ASTAGE(bi, sv)                                        \
  do {                                                        \
    gload_lds16(kS + (long)(sv) * ND, Ks0 + (bi) * 4096 + wv * 512); \
    gload_lds16(vS + (sv), Vs0 + (bi) * 4096 + wv * 512);     \
  } while (0)

  const int swz = (ql & 7) << 4;

  ASTAGE(0, 0);
  int cur = 0, nxt = 1;

  for (int s0 = 0; s0 < NS; s0 += 64) {
    if (s0 + 64 < NS) {
      ASTAGE(nxt, s0 + 64);
      asm volatile("s_waitcnt vmcnt(2)" ::: "memory");
    } else {
      VM_DRAIN();
    }
    BARRIER();
    __builtin_amdgcn_sched_barrier(0);
    const char* KsB = (const char*)(Ks0 + cur * 4096);
    const char* VsB = (const char*)(Vs0 + cur * 4096);

    f32x16 st0 = {}, st1 = {};
    __builtin_amdgcn_s_setprio(1);
#pragma unroll
    for (int cd = 0; cd < 4; cd++) {
      bf16x8 kf0 = *(const bf16x8*)(KsB + ql * 128 + ((cd * 32 + hi * 16) ^ swz));
      st0 = mfma32(kf0, qf[cd], st0);
      bf16x8 kf1 = *(const bf16x8*)(KsB + (32 + ql) * 128 + ((cd * 32 + hi * 16) ^ swz));
      st1 = mfma32(kf1, qf[cd], st1);
    }
    __builtin_amdgcn_s_setprio(0);

    if (!((cw >> (s0 >> 6)) & 1)) {
#pragma unroll
      for (int t = 0; t < 4; t++) {
        float4 m0 = *(const float4*)(mbp + s0 + t * 8 + hi * 4);
        st0[4 * t + 0] += m0.x;
        st0[4 * t + 1] += m0.y;
        st0[4 * t + 2] += m0.z;
        st0[4 * t + 3] += m0.w;
        float4 m1 = *(const float4*)(mbp + s0 + 32 + t * 8 + hi * 4);
        st1[4 * t + 0] += m1.x;
        st1[4 * t + 1] += m1.y;
        st1[4 * t + 2] += m1.z;
        st1[4 * t + 3] += m1.w;
      }
    }

#pragma unroll
    for (int i = 0; i < 16; i++) {
      st0[i] = expv(st0[i]);
      st1[i] = expv(st1[i]);
    }
    float u[16];
#pragma unroll
    for (int i = 0; i < 16; i++) u[i] = st0[i] + st1[i];
#pragma unroll
    for (int off = 8; off; off >>= 1)
#pragma unroll
      for (int i = 0; i < off; i++) u[i] += u[i + off];
    lrun += u[0];

    union {
      uint u[16];
      bf16x8 f[4];
    } pw;
    {
      uint c0 = cvtpk(st0[0], st0[1]), c1 = cvtpk(st0[4], st0[5]);
      swap32u(c0, c1);
      uint d0 = cvtpk(st0[2], st0[3]), d1 = cvtpk(st0[6], st0[7]);
      swap32u(d0, d1);
      pw.u[0] = c0; pw.u[1] = d0; pw.u[2] = c1; pw.u[3] = d1;
      uint e0 = cvtpk(st0[8], st0[9]), e1 = cvtpk(st0[12], st0[13]);
      swap32u(e0, e1);
      uint f0 = cvtpk(st0[10], st0[11]), f1 = cvtpk(st0[14], st0[15]);
      swap32u(f0, f1);
      pw.u[4] = e0; pw.u[5] = f0; pw.u[6] = e1; pw.u[7] = f1;
    }
    {
      uint c0 = cvtpk(st1[0], st1[1]), c1 = cvtpk(st1[4], st1[5]);
      swap32u(c0, c1);
      uint d0 = cvtpk(st1[2], st1[3]), d1 = cvtpk(st1[6], st1[7]);
      swap32u(d0, d1);
      pw.u[8] = c0; pw.u[9] = d0; pw.u[10] = c1; pw.u[11] = d1;
      uint e0 = cvtpk(st1[8], st1[9]), e1 = cvtpk(st1[12], st1[13]);
      swap32u(e0, e1);
      uint f0 = cvtpk(st1[10], st1[11]), f1 = cvtpk(st1[14], st1[15]);
      swap32u(f0, f1);
      pw.u[12] = e0; pw.u[13] = f0; pw.u[14] = e1; pw.u[15] = f1;
    }

    __builtin_amdgcn_s_setprio(1);
#pragma unroll
    for (int dt = 0; dt < 2; dt++) {
#pragma unroll
      for (int ck = 0; ck < 4; ck++) {
        bf16x8 vf = *(const bf16x8*)(VsB + (dt * 32 + ql) * 128 +
                                     ((ck * 32 + hi * 16) ^ swz));
        o[dt] = mfma32(vf, pw.f[ck], o[dt]);
      }
    }
    __builtin_amdgcn_s_setprio(0);
    cur = nxt;
    nxt = (nxt == 2) ? 0 : nxt + 1;
  }
#undef ASTAGE

  lrun += __shfl_xor(lrun, 32);
  const float invL = 1.0f / lrun;
  bf16* op = ctx + ((long)(b * NS + q0 + ql)) * ND + h * NHD;
#pragma unroll
  for (int dt = 0; dt < 2; dt++) {
#pragma unroll
    for (int t = 0; t < 4; t++) {
      bf16x4 pk;
#pragma unroll
      for (int i = 0; i < 4; i++) pk[i] = (bf16)(o[dt][t * 4 + i] * invL);
      *(bf16x4*)(op + dt * 32 + t * 8 + hi * 4) = pk;
    }
  }
}

extern "C" void kernel_launch(void* const* d_in, const int* in_sizes, int n_in,
                              void* d_out, int out_size, void* d_ws, size_t ws_size,
                              hipStream_t stream) {
  const float* value = (const float*)d_in[0];
  const float* key_t = (const float*)d_in[1];
  const float* query = (const float*)d_in[2];
  const int* mask = (const int*)d_in[3];
  const float* W_q = (const float*)d_in[4];
  const float* W_k = (const float*)d_in[5];
  const float* W_v = (const float*)d_in[6];
  const float* W_o = (const float*)d_in[7];
  const float* b_o = (const float*)d_in[8];
  float* out = (float*)d_out;

  char* ws = (char*)d_ws;
  bf16* wb = (bf16*)(ws + 0);                // 8MiB: wq, wk, wv, wo (bf16)
  bf16* Qb = (bf16*)(ws + (8UL << 20));      // 16MiB
  bf16* Kb = (bf16*)(ws + (24UL << 20));     // 16MiB
  bf16* Vtb = (bf16*)(ws + (40UL << 20));    // 16MiB (pre-transposed V)
  bf16* ctx = (bf16*)(ws + (56UL << 20));    // 16MiB
  float* mbias = (float*)(ws + (72UL << 20));
  uint* cleanwd = (uint*)(ws + (72UL << 20) + 32768);

  const int nW4 = (ND * ND) / 4;
  // HD^-0.5 * log2(e) folded into W_q -> logits in base-2 units
  const float hscale = 0.125f * 1.44269504088896f;

  prep<<<4129, 256, 0, stream>>>((const float4*)W_q, (const float4*)W_k,
                                 (const float4*)W_v, (const float4*)W_o,
                                 (bf16x4*)wb, hscale, nW4,
                                 mask, mbias, cleanwd, NB * NS);
  bf16* wob = wb + 3L * ND * ND;

  proj_gemm<<<1536, 256, 0, stream>>>(query, key_t, value, wb, Qb, Kb, Vtb);

  attn_fwd4<<<512, 512, 0, stream>>>(Qb, Kb, Vtb, mbias, cleanwd, ctx);

  gemm_out<<<(ND / 64) * ((NB * NS) / 128), 256, 0, stream>>>(
      ctx, wob, out, b_o, NB * NS, ND, ND);
}

// Round 14
// 225.168 us; speedup vs baseline: 1.0246x; 1.0246x over previous
//
#include <hip/hip_runtime.h>
#include <hip/hip_bf16.h>

typedef __bf16 bf16;
typedef __bf16 bf16x8 __attribute__((ext_vector_type(8)));
typedef __bf16 bf16x4 __attribute__((ext_vector_type(4)));
typedef float f32x4 __attribute__((ext_vector_type(4)));
typedef float f32x16 __attribute__((ext_vector_type(16)));
typedef unsigned int uint;

#define NB 4
#define NS 2048
#define ND 1024
#define NHH 16
#define NHD 64

__device__ __forceinline__ void gload_lds16(const void* g, void* l) {
  __builtin_amdgcn_global_load_lds((const __attribute__((address_space(1))) void*)g,
                                   (__attribute__((address_space(3))) void*)l, 16, 0, 0);
}

__device__ __forceinline__ f32x4 mfma16(bf16x8 a, bf16x8 b, f32x4 c) {
  return __builtin_amdgcn_mfma_f32_16x16x32_bf16(a, b, c, 0, 0, 0);
}
__device__ __forceinline__ f32x16 mfma32(bf16x8 a, bf16x8 b, f32x16 c) {
  return __builtin_amdgcn_mfma_f32_32x32x16_bf16(a, b, c, 0, 0, 0);
}
__device__ __forceinline__ uint cvtpk(float lo, float hi) {
  uint r;
  asm("v_cvt_pk_bf16_f32 %0, %1, %2" : "=v"(r) : "v"(lo), "v"(hi));
  return r;
}
__device__ __forceinline__ void swap32u(uint& a, uint& b) {
  asm("v_permlane32_swap_b32 %0, %1" : "+v"(a), "+v"(b));
}
__device__ __forceinline__ float expv(float x) {
  float r;
  asm("v_exp_f32 %0, %1" : "=v"(r) : "v"(x));
  return r;
}
#define BARRIER()                          \
  do {                                     \
    asm volatile("" ::: "memory");         \
    __builtin_amdgcn_s_barrier();          \
    asm volatile("" ::: "memory");         \
  } while (0)

// ---------------- f32 -> bf16 convert ----------------
__global__ __launch_bounds__(256) void cvt_bf16(const float4* __restrict__ in,
                                                bf16x4* __restrict__ out,
                                                float scale, int n4) {
  int i = blockIdx.x * 256 + threadIdx.x;
  if (i < n4) {
    float4 v = in[i];
    bf16x4 o;
    o[0] = (bf16)(v.x * scale);
    o[1] = (bf16)(v.y * scale);
    o[2] = (bf16)(v.z * scale);
    o[3] = (bf16)(v.w * scale);
    out[i] = o;
  }
}

// --- fused prep: 4 weights->bf16 | mask->bias | mask->packed clean bits ---
__global__ __launch_bounds__(256) void prep(
    const float4* __restrict__ w0, const float4* __restrict__ w1,
    const float4* __restrict__ w2, const float4* __restrict__ w3,
    bf16x4* __restrict__ wout, float scale0, int n4each,
    const int* __restrict__ m, float* __restrict__ mb,
    uint* __restrict__ cleanw, int nmask) {
  const int bid = blockIdx.x;
  if (bid < 4096) {
    int i = bid * 256 + threadIdx.x;
    int w = i / n4each;
    int j = i - w * n4each;
    const float4* src = (w == 0) ? w0 : (w == 1) ? w1 : (w == 2) ? w2 : w3;
    float sc = (w == 0) ? scale0 : 1.0f;
    float4 v = src[j];
    bf16x4 o;
    o[0] = (bf16)(v.x * sc);
    o[1] = (bf16)(v.y * sc);
    o[2] = (bf16)(v.z * sc);
    o[3] = (bf16)(v.w * sc);
    wout[i] = o;
  } else if (bid < 4128) {
    int i = (bid - 4096) * 256 + threadIdx.x;
    if (i < nmask) mb[i] = m[i] ? 0.0f : -3e38f;
  } else {
    int i = threadIdx.x;
    if (i < 128) {
      const int* p = m + i * 64;
      int all1 = 1;
#pragma unroll
      for (int j = 0; j < 64; j += 4) {
        int4 v = *(const int4*)(p + j);
        all1 &= (v.x && v.y && v.z && v.w) ? 1 : 0;
      }
      unsigned long long bal = __ballot(all1);
      int wv = i >> 6, lane = i & 63;
      if (lane == 0) {
        cleanw[2 * wv] = (uint)bal;
        cleanw[2 * wv + 1] = (uint)(bal >> 32);
      }
    }
  }
}

// ---- unified 128x128 bf16 GEMM, C = A @ B^T ----
// 4 waves (2x2, wave-tile 64x64, acc[4][4]); BK=32, 32 K-steps.
// 3-buffer LDS (As[3]+Bs[3] = 48KB -> 3 blocks/CU), stage issued 2 tiles
// ahead, ONE barrier/iter, in-loop vmcnt(4): queue holds tile-t's 4 loads
// (issued at t-2, ~2 iters of slack) + t+1's 4; wait releases when t's
// retire. Buffer safety: stage(t+2) -> buf[(t+2)%3], whose readers ran at
// t-1 and retired (MFMA-consumed) before barrier(t). R7-proven rotation.
// EPI: 0 = bf16 C; 1 = V transposed to Vt[bh][d][s]; 2 = bias+erf-GELU f32.
template <int EPI>
__global__ __launch_bounds__(256) void gemm8(
    const bf16* __restrict__ A, const bf16* __restrict__ Bw,
    bf16* __restrict__ Cb, float* __restrict__ Cf,
    const float* __restrict__ bias, int M, int N, int K) {
  __shared__ bf16 As[3][4096];
  __shared__ bf16 Bs[3][4096];
  bf16* As0 = &As[0][0];
  bf16* Bs0 = &Bs[0][0];
  const int tid = threadIdx.x;
  const int lane = tid & 63, wv = tid >> 6;
  const int wr = wv >> 1, wc = wv & 1;
  const int g = lane >> 4, r = lane & 15;
  const int nx = N >> 7;
  const int chunk = gridDim.x >> 3;
  const int bid = blockIdx.x;
  const int wg = (bid & 7) * chunk + (bid >> 3);  // grid % 8 == 0: bijective
  const int colBase = (wg % nx) * 128;
  const int rowBase = (wg / nx) * 128;

  const int sRow = wv * 16 + (lane >> 2);
  const int sK = (lane & 3) * 8;
  const bf16* aj0 = A + (long)(rowBase + sRow) * K + sK;
  const bf16* aj1 = aj0 + 64L * K;
  const bf16* bj0 = Bw + (long)(colBase + sRow) * K + sK;
  const bf16* bj1 = bj0 + 64L * K;

#define GSTAGE(bi, kk)                                      \
  do {                                                      \
    gload_lds16(aj0 + (kk), As0 + (bi) * 4096 + wv * 512);  \
    gload_lds16(aj1 + (kk), As0 + (bi) * 4096 + 2048 + wv * 512); \
    gload_lds16(bj0 + (kk), Bs0 + (bi) * 4096 + wv * 512);  \
    gload_lds16(bj1 + (kk), Bs0 + (bi) * 4096 + 2048 + wv * 512); \
  } while (0)

  f32x4 acc[4][4] = {};

  GSTAGE(0, 0);
  GSTAGE(1, 32);
  int cur = 0, nxt2 = 2;  // buffer of tile t, buffer of tile t+2

  for (int k0 = 0; k0 < K; k0 += 32) {
    if (k0 + 32 < K) {
      asm volatile("s_waitcnt vmcnt(4)" ::: "memory");  // tile-t landed
    } else {
      asm volatile("s_waitcnt vmcnt(0)" ::: "memory");
    }
    BARRIER();  // all waves: tile-t staged; buf[nxt2] readers (t-1) retired
    __builtin_amdgcn_sched_barrier(0);
    if (k0 + 64 < K) GSTAGE(nxt2, k0 + 64);

    const bf16* Ac = As0 + cur * 4096;
    const bf16* Bc = Bs0 + cur * 4096;
    bf16x8 af[4], bfr[4];
#pragma unroll
    for (int m = 0; m < 4; m++)
      af[m] = *(const bf16x8*)(Ac + (wr * 64 + m * 16 + r) * 32 + g * 8);
#pragma unroll
    for (int n = 0; n < 4; n++)
      bfr[n] = *(const bf16x8*)(Bc + (wc * 64 + n * 16 + r) * 32 + g * 8);
    __builtin_amdgcn_s_setprio(1);
#pragma unroll
    for (int m = 0; m < 4; m++)
#pragma unroll
      for (int n = 0; n < 4; n++)
        acc[m][n] = mfma16(af[m], bfr[n], acc[m][n]);
    __builtin_amdgcn_s_setprio(0);
    cur = (cur == 2) ? 0 : cur + 1;
    nxt2 = (nxt2 == 2) ? 0 : nxt2 + 1;
  }
#undef GSTAGE

  if (EPI == 0) {
#pragma unroll
    for (int m = 0; m < 4; m++)
#pragma unroll
      for (int n = 0; n < 4; n++)
#pragma unroll
        for (int q = 0; q < 4; q++) {
          int row = rowBase + wr * 64 + m * 16 + 4 * g + q;
          int col = colBase + wc * 64 + n * 16 + r;
          Cb[(long)row * N + col] = (bf16)acc[m][n][q];
        }
  } else if (EPI == 1) {
    // V transposed: Vt[bh][d][s]; s = (rowBase&2047) + wr*64 + m*16 + 4g + q
    const int b = rowBase >> 11;
    const int sbase = (rowBase & 2047) + wr * 64;
#pragma unroll
    for (int m = 0; m < 4; m++) {
#pragma unroll
      for (int n = 0; n < 4; n++) {
        int col = colBase + wc * 64 + n * 16 + r;
        int h = col >> 6, d = col & 63;
        bf16x4 pk;
#pragma unroll
        for (int q = 0; q < 4; q++) pk[q] = (bf16)acc[m][n][q];
        *(bf16x4*)(Cb + ((long)(b * NHH + h) * NHD + d) * NS + sbase + m * 16 + 4 * g) = pk;
      }
    }
  } else {
#pragma unroll
    for (int m = 0; m < 4; m++)
#pragma unroll
      for (int n = 0; n < 4; n++)
#pragma unroll
        for (int q = 0; q < 4; q++) {
          int row = rowBase + wr * 64 + m * 16 + 4 * g + q;
          int col = colBase + wc * 64 + n * 16 + r;
          float v = acc[m][n][q] + bias[col];
          v = 0.5f * v * (1.0f + erff(v * 0.70710678118654752f));
          Cf[(long)row * N + col] = v;
        }
  }
}

// ------- flash attention: 8-wave, swapped-operand, shift-free softmax ----
// QBLK=256 (8 waves x 32 q-rows), KBLK=64. 3-buffer/1-barrier counted-vmcnt
// pipeline. 1 K-load + 1 V-load per wave per tile -> vmcnt(2). grid 512,
// XCD-swizzled. Logits base-2 (log2e folded into W_q): p = 2^st.
__global__ __launch_bounds__(512) void attn_fwd4(
    const bf16* __restrict__ Q, const bf16* __restrict__ K,
    const bf16* __restrict__ Vt, const float* __restrict__ mbias,
    const uint* __restrict__ cleanw, bf16* __restrict__ ctx) {
  __shared__ bf16 Ks[3][64 * 64];
  __shared__ bf16 Vs[3][64 * 64];
  bf16* Ks0 = &Ks[0][0];
  bf16* Vs0 = &Vs[0][0];
  const int tid = threadIdx.x;
  const int lane = tid & 63, wv = tid >> 6;
  const int ql = lane & 31, hi = lane >> 5;
  const int g = blockIdx.x;
  const int gx = (g & 63) >> 3;
  const int bh = ((g >> 6) << 3) | (g & 7);
  const int b = bh >> 4, h = bh & 15;
  const int q0 = gx * 256 + wv * 32;

  const bf16* Qp = Q + ((long)(b * NS + q0 + ql)) * ND + h * NHD;
  const bf16* Kp = K + ((long)b * NS) * ND + h * NHD;
  const bf16* Vp = Vt + (long)bh * NHD * NS;
  const float* mbp = mbias + b * NS;
  const uint cw = cleanw[b];

  bf16x8 qf[4];
#pragma unroll
  for (int cd = 0; cd < 4; cd++)
    qf[cd] = *(const bf16x8*)(Qp + cd * 16 + hi * 8);

  f32x16 o[2] = {};
  float lrun = 0.f;

  const int Lrow = wv * 8 + (lane >> 3);
  const int scb = ((lane & 7) * 16) ^ ((Lrow & 7) << 4);
  const bf16* kS = Kp + (long)Lrow * ND + (scb >> 1);
  const bf16* vS = Vp + (long)Lrow * NS + (scb >> 1);

#define ASTAGE(bi, sv)                                        \
  do {                                                        \
    gload_lds16(kS + (long)(sv) * ND, Ks0 + (bi) * 4096 + wv * 512); \
    gload_lds16(vS + (sv), Vs0 + (bi) * 4096 + wv * 512);     \
  } while (0)

  const int swz = (ql & 7) << 4;

  ASTAGE(0, 0);
  int cur = 0, nxt = 1;

  for (int s0 = 0; s0 < NS; s0 += 64) {
    if (s0 + 64 < NS) {
      ASTAGE(nxt, s0 + 64);
      asm volatile("s_waitcnt vmcnt(2)" ::: "memory");
    } else {
      asm volatile("s_waitcnt vmcnt(0)" ::: "memory");
    }
    BARRIER();
    __builtin_amdgcn_sched_barrier(0);
    const char* KsB = (const char*)(Ks0 + cur * 4096);
    const char* VsB = (const char*)(Vs0 + cur * 4096);

    f32x16 st0 = {}, st1 = {};
    __builtin_amdgcn_s_setprio(1);
#pragma unroll
    for (int cd = 0; cd < 4; cd++) {
      bf16x8 kf0 = *(const bf16x8*)(KsB + ql * 128 + ((cd * 32 + hi * 16) ^ swz));
      st0 = mfma32(kf0, qf[cd], st0);
      bf16x8 kf1 = *(const bf16x8*)(KsB + (32 + ql) * 128 + ((cd * 32 + hi * 16) ^ swz));
      st1 = mfma32(kf1, qf[cd], st1);
    }
    __builtin_amdgcn_s_setprio(0);

    if (!((cw >> (s0 >> 6)) & 1)) {
#pragma unroll
      for (int t = 0; t < 4; t++) {
        float4 m0 = *(const float4*)(mbp + s0 + t * 8 + hi * 4);
        st0[4 * t + 0] += m0.x;
        st0[4 * t + 1] += m0.y;
        st0[4 * t + 2] += m0.z;
        st0[4 * t + 3] += m0.w;
        float4 m1 = *(const float4*)(mbp + s0 + 32 + t * 8 + hi * 4);
        st1[4 * t + 0] += m1.x;
        st1[4 * t + 1] += m1.y;
        st1[4 * t + 2] += m1.z;
        st1[4 * t + 3] += m1.w;
      }
    }

#pragma unroll
    for (int i = 0; i < 16; i++) {
      st0[i] = expv(st0[i]);
      st1[i] = expv(st1[i]);
    }
    float u[16];
#pragma unroll
    for (int i = 0; i < 16; i++) u[i] = st0[i] + st1[i];
#pragma unroll
    for (int off = 8; off; off >>= 1)
#pragma unroll
      for (int i = 0; i < off; i++) u[i] += u[i + off];
    lrun += u[0];

    union {
      uint u[16];
      bf16x8 f[4];
    } pw;
    {
      uint c0 = cvtpk(st0[0], st0[1]), c1 = cvtpk(st0[4], st0[5]);
      swap32u(c0, c1);
      uint d0 = cvtpk(st0[2], st0[3]), d1 = cvtpk(st0[6], st0[7]);
      swap32u(d0, d1);
      pw.u[0] = c0; pw.u[1] = d0; pw.u[2] = c1; pw.u[3] = d1;
      uint e0 = cvtpk(st0[8], st0[9]), e1 = cvtpk(st0[12], st0[13]);
      swap32u(e0, e1);
      uint f0 = cvtpk(st0[10], st0[11]), f1 = cvtpk(st0[14], st0[15]);
      swap32u(f0, f1);
      pw.u[4] = e0; pw.u[5] = f0; pw.u[6] = e1; pw.u[7] = f1;
    }
    {
      uint c0 = cvtpk(st1[0], st1[1]), c1 = cvtpk(st1[4], st1[5]);
      swap32u(c0, c1);
      uint d0 = cvtpk(st1[2], st1[3]), d1 = cvtpk(st1[6], st1[7]);
      swap32u(d0, d1);
      pw.u[8] = c0; pw.u[9] = d0; pw.u[10] = c1; pw.u[11] = d1;
      uint e0 = cvtpk(st1[8], st1[9]), e1 = cvtpk(st1[12], st1[13]);
      swap32u(e0, e1);
      uint f0 = cvtpk(st1[10], st1[11]), f1 = cvtpk(st1[14], st1[15]);
      swap32u(f0, f1);
      pw.u[12] = e0; pw.u[13] = f0; pw.u[14] = e1; pw.u[15] = f1;
    }

    __builtin_amdgcn_s_setprio(1);
#pragma unroll
    for (int dt = 0; dt < 2; dt++) {
#pragma unroll
      for (int ck = 0; ck < 4; ck++) {
        bf16x8 vf = *(const bf16x8*)(VsB + (dt * 32 + ql) * 128 +
                                     ((ck * 32 + hi * 16) ^ swz));
        o[dt] = mfma32(vf, pw.f[ck], o[dt]);
      }
    }
    __builtin_amdgcn_s_setprio(0);
    cur = nxt;
    nxt = (nxt == 2) ? 0 : nxt + 1;
  }
#undef ASTAGE

  lrun += __shfl_xor(lrun, 32);
  const float invL = 1.0f / lrun;
  bf16* op = ctx + ((long)(b * NS + q0 + ql)) * ND + h * NHD;
#pragma unroll
  for (int dt = 0; dt < 2; dt++) {
#pragma unroll
    for (int t = 0; t < 4; t++) {
      bf16x4 pk;
#pragma unroll
      for (int i = 0; i < 4; i++) pk[i] = (bf16)(o[dt][t * 4 + i] * invL);
      *(bf16x4*)(op + dt * 32 + t * 8 + hi * 4) = pk;
    }
  }
}

extern "C" void kernel_launch(void* const* d_in, const int* in_sizes, int n_in,
                              void* d_out, int out_size, void* d_ws, size_t ws_size,
                              hipStream_t stream) {
  const float* value = (const float*)d_in[0];
  const float* key_t = (const float*)d_in[1];
  const float* query = (const float*)d_in[2];
  const int* mask = (const int*)d_in[3];
  const float* W_q = (const float*)d_in[4];
  const float* W_k = (const float*)d_in[5];
  const float* W_v = (const float*)d_in[6];
  const float* W_o = (const float*)d_in[7];
  const float* b_o = (const float*)d_in[8];
  float* out = (float*)d_out;

  char* ws = (char*)d_ws;
  bf16* Axb = (bf16*)(ws + 0);               // 16MB A-bf16 staging; later ctx
  bf16* ctx = (bf16*)(ws + 0);               // (attn output; Axb dead by then)
  bf16* wb = (bf16*)(ws + (16UL << 20));     // 8MB: wq, wk, wv, wo
  bf16* Qb = (bf16*)(ws + (24UL << 20));     // 16MB
  bf16* Kb = (bf16*)(ws + (40UL << 20));     // 16MB
  bf16* Vtb = (bf16*)(ws + (56UL << 20));    // 16MB (pre-transposed V)
  float* mbias = (float*)(ws + (72UL << 20));
  uint* cleanwd = (uint*)(ws + (72UL << 20) + 32768);

  const int nX4 = (NB * NS * ND) / 4;  // 2M float4
  const int nW4 = (ND * ND) / 4;
  // HD^-0.5 * log2(e) folded into W_q -> logits in base-2 units
  const float hscale = 0.125f * 1.44269504088896f;

  prep<<<4129, 256, 0, stream>>>((const float4*)W_q, (const float4*)W_k,
                                 (const float4*)W_v, (const float4*)W_o,
                                 (bf16x4*)wb, hscale, nW4,
                                 mask, mbias, cleanwd, NB * NS);
  bf16* wqb = wb;
  bf16* wkb = wb + 1L * ND * ND;
  bf16* wvb = wb + 2L * ND * ND;
  bf16* wob = wb + 3L * ND * ND;

  const int ggrid = ((NB * NS) / 128) * (ND / 128);  // 64 * 8 = 512

  cvt_bf16<<<nX4 / 256, 256, 0, stream>>>((const float4*)query, (bf16x4*)Axb, 1.0f, nX4);
  gemm8<0><<<ggrid, 256, 0, stream>>>(Axb, wqb, Qb, nullptr, nullptr, NB * NS, ND, ND);

  cvt_bf16<<<nX4 / 256, 256, 0, stream>>>((const float4*)key_t, (bf16x4*)Axb, 1.0f, nX4);
  gemm8<0><<<ggrid, 256, 0, stream>>>(Axb, wkb, Kb, nullptr, nullptr, NB * NS, ND, ND);

  cvt_bf16<<<nX4 / 256, 256, 0, stream>>>((const float4*)value, (bf16x4*)Axb, 1.0f, nX4);
  gemm8<1><<<ggrid, 256, 0, stream>>>(Axb, wvb, Vtb, nullptr, nullptr, NB * NS, ND, ND);

  attn_fwd4<<<512, 512, 0, stream>>>(Qb, Kb, Vtb, mbias, cleanwd, ctx);

  gemm8<2><<<ggrid, 256, 0, stream>>>(ctx, wob, nullptr, out, b_o, NB * NS, ND, ND);
}

// Round 15
// 223.298 us; speedup vs baseline: 1.0332x; 1.0084x over previous
//
#include <hip/hip_runtime.h>
#include <hip/hip_bf16.h>

typedef __bf16 bf16;
typedef __bf16 bf16x8 __attribute__((ext_vector_type(8)));
typedef __bf16 bf16x4 __attribute__((ext_vector_type(4)));
typedef float f32x4 __attribute__((ext_vector_type(4)));
typedef float f32x16 __attribute__((ext_vector_type(16)));
typedef unsigned int uint;

#define NB 4
#define NS 2048
#define ND 1024
#define NHH 16
#define NHD 64

__device__ __forceinline__ void gload_lds16(const void* g, void* l) {
  __builtin_amdgcn_global_load_lds((const __attribute__((address_space(1))) void*)g,
                                   (__attribute__((address_space(3))) void*)l, 16, 0, 0);
}

__device__ __forceinline__ f32x4 mfma16(bf16x8 a, bf16x8 b, f32x4 c) {
  return __builtin_amdgcn_mfma_f32_16x16x32_bf16(a, b, c, 0, 0, 0);
}
__device__ __forceinline__ f32x16 mfma32(bf16x8 a, bf16x8 b, f32x16 c) {
  return __builtin_amdgcn_mfma_f32_32x32x16_bf16(a, b, c, 0, 0, 0);
}
__device__ __forceinline__ uint cvtpk(float lo, float hi) {
  uint r;
  asm("v_cvt_pk_bf16_f32 %0, %1, %2" : "=v"(r) : "v"(lo), "v"(hi));
  return r;
}
__device__ __forceinline__ void swap32u(uint& a, uint& b) {
  asm("v_permlane32_swap_b32 %0, %1" : "+v"(a), "+v"(b));
}
__device__ __forceinline__ float expv(float x) {
  float r;
  asm("v_exp_f32 %0, %1" : "=v"(r) : "v"(x));
  return r;
}
#define BARRIER()                          \
  do {                                     \
    asm volatile("" ::: "memory");         \
    __builtin_amdgcn_s_barrier();          \
    asm volatile("" ::: "memory");         \
  } while (0)

// ---------------- f32 -> bf16 convert ----------------
__global__ __launch_bounds__(256) void cvt_bf16(const float4* __restrict__ in,
                                                bf16x4* __restrict__ out,
                                                float scale, int n4) {
  int i = blockIdx.x * 256 + threadIdx.x;
  if (i < n4) {
    float4 v = in[i];
    bf16x4 o;
    o[0] = (bf16)(v.x * scale);
    o[1] = (bf16)(v.y * scale);
    o[2] = (bf16)(v.z * scale);
    o[3] = (bf16)(v.w * scale);
    out[i] = o;
  }
}

// --- fused prep: 4 weights->bf16 | mask->bias | mask->packed clean bits ---
__global__ __launch_bounds__(256) void prep(
    const float4* __restrict__ w0, const float4* __restrict__ w1,
    const float4* __restrict__ w2, const float4* __restrict__ w3,
    bf16x4* __restrict__ wout, float scale0, int n4each,
    const int* __restrict__ m, float* __restrict__ mb,
    uint* __restrict__ cleanw, int nmask) {
  const int bid = blockIdx.x;
  if (bid < 4096) {
    int i = bid * 256 + threadIdx.x;
    int w = i / n4each;
    int j = i - w * n4each;
    const float4* src = (w == 0) ? w0 : (w == 1) ? w1 : (w == 2) ? w2 : w3;
    float sc = (w == 0) ? scale0 : 1.0f;
    float4 v = src[j];
    bf16x4 o;
    o[0] = (bf16)(v.x * sc);
    o[1] = (bf16)(v.y * sc);
    o[2] = (bf16)(v.z * sc);
    o[3] = (bf16)(v.w * sc);
    wout[i] = o;
  } else if (bid < 4128) {
    int i = (bid - 4096) * 256 + threadIdx.x;
    if (i < nmask) mb[i] = m[i] ? 0.0f : -3e38f;
  } else {
    int i = threadIdx.x;
    if (i < 128) {
      const int* p = m + i * 64;
      int all1 = 1;
#pragma unroll
      for (int j = 0; j < 64; j += 4) {
        int4 v = *(const int4*)(p + j);
        all1 &= (v.x && v.y && v.z && v.w) ? 1 : 0;
      }
      unsigned long long bal = __ballot(all1);
      int wv = i >> 6, lane = i & 63;
      if (lane == 0) {
        cleanw[2 * wv] = (uint)bal;
        cleanw[2 * wv + 1] = (uint)(bal >> 32);
      }
    }
  }
}

// ---- unified 128x128 bf16 GEMM, C = A @ B^T ----
// 3-buffer depth-2 counted-vmcnt pipeline (R14-proven). NEW: both-sides LDS
// slot swizzle (R13-proven pair in this exact [128][32] geometry):
//   staging source slot = (lane&3) ^ ((lane>>3)&3)  (linear LDS dest)
//   fragment read slot  = g ^ ((r>>1)&3)
// -> per-16-lane-phase bank pattern goes 8-way -> 2-way (free, m136).
// EPI: 0 = bf16 C; 1 = V transposed to Vt[bh][d][s]; 2 = bias+erf-GELU f32.
template <int EPI>
__global__ __launch_bounds__(256) void gemm8(
    const bf16* __restrict__ A, const bf16* __restrict__ Bw,
    bf16* __restrict__ Cb, float* __restrict__ Cf,
    const float* __restrict__ bias, int M, int N, int K) {
  __shared__ bf16 As[3][4096];
  __shared__ bf16 Bs[3][4096];
  bf16* As0 = &As[0][0];
  bf16* Bs0 = &Bs[0][0];
  const int tid = threadIdx.x;
  const int lane = tid & 63, wv = tid >> 6;
  const int wr = wv >> 1, wc = wv & 1;
  const int g = lane >> 4, r = lane & 15;
  const int nx = N >> 7;
  const int chunk = gridDim.x >> 3;
  const int bid = blockIdx.x;
  const int wg = (bid & 7) * chunk + (bid >> 3);  // grid % 8 == 0: bijective
  const int colBase = (wg % nx) * 128;
  const int rowBase = (wg / nx) * 128;

  const int sRow = wv * 16 + (lane >> 2);
  const int sK = ((lane & 3) ^ ((lane >> 3) & 3)) * 8;  // source pre-swizzle
  const bf16* aj0 = A + (long)(rowBase + sRow) * K + sK;
  const bf16* aj1 = aj0 + 64L * K;
  const bf16* bj0 = Bw + (long)(colBase + sRow) * K + sK;
  const bf16* bj1 = bj0 + 64L * K;

#define GSTAGE(bi, kk)                                      \
  do {                                                      \
    gload_lds16(aj0 + (kk), As0 + (bi) * 4096 + wv * 512);  \
    gload_lds16(aj1 + (kk), As0 + (bi) * 4096 + 2048 + wv * 512); \
    gload_lds16(bj0 + (kk), Bs0 + (bi) * 4096 + wv * 512);  \
    gload_lds16(bj1 + (kk), Bs0 + (bi) * 4096 + 2048 + wv * 512); \
  } while (0)

  f32x4 acc[4][4] = {};
  const int gs = (g ^ ((r >> 1) & 3)) * 8;  // swizzled read slot

  GSTAGE(0, 0);
  GSTAGE(1, 32);
  int cur = 0, nxt2 = 2;  // buffer of tile t, buffer of tile t+2

  for (int k0 = 0; k0 < K; k0 += 32) {
    if (k0 + 32 < K) {
      asm volatile("s_waitcnt vmcnt(4)" ::: "memory");  // tile-t landed
    } else {
      asm volatile("s_waitcnt vmcnt(0)" ::: "memory");
    }
    BARRIER();  // all waves: tile-t staged; buf[nxt2] readers (t-1) retired
    __builtin_amdgcn_sched_barrier(0);
    if (k0 + 64 < K) GSTAGE(nxt2, k0 + 64);

    const bf16* Ac = As0 + cur * 4096;
    const bf16* Bc = Bs0 + cur * 4096;
    bf16x8 af[4], bfr[4];
#pragma unroll
    for (int m = 0; m < 4; m++)
      af[m] = *(const bf16x8*)(Ac + (wr * 64 + m * 16 + r) * 32 + gs);
#pragma unroll
    for (int n = 0; n < 4; n++)
      bfr[n] = *(const bf16x8*)(Bc + (wc * 64 + n * 16 + r) * 32 + gs);
    __builtin_amdgcn_s_setprio(1);
#pragma unroll
    for (int m = 0; m < 4; m++)
#pragma unroll
      for (int n = 0; n < 4; n++)
        acc[m][n] = mfma16(af[m], bfr[n], acc[m][n]);
    __builtin_amdgcn_s_setprio(0);
    cur = (cur == 2) ? 0 : cur + 1;
    nxt2 = (nxt2 == 2) ? 0 : nxt2 + 1;
  }
#undef GSTAGE

  if (EPI == 0) {
#pragma unroll
    for (int m = 0; m < 4; m++)
#pragma unroll
      for (int n = 0; n < 4; n++)
#pragma unroll
        for (int q = 0; q < 4; q++) {
          int row = rowBase + wr * 64 + m * 16 + 4 * g + q;
          int col = colBase + wc * 64 + n * 16 + r;
          Cb[(long)row * N + col] = (bf16)acc[m][n][q];
        }
  } else if (EPI == 1) {
    // V transposed: Vt[bh][d][s]; s = (rowBase&2047) + wr*64 + m*16 + 4g + q
    const int b = rowBase >> 11;
    const int sbase = (rowBase & 2047) + wr * 64;
#pragma unroll
    for (int m = 0; m < 4; m++) {
#pragma unroll
      for (int n = 0; n < 4; n++) {
        int col = colBase + wc * 64 + n * 16 + r;
        int h = col >> 6, d = col & 63;
        bf16x4 pk;
#pragma unroll
        for (int q = 0; q < 4; q++) pk[q] = (bf16)acc[m][n][q];
        *(bf16x4*)(Cb + ((long)(b * NHH + h) * NHD + d) * NS + sbase + m * 16 + 4 * g) = pk;
      }
    }
  } else {
#pragma unroll
    for (int m = 0; m < 4; m++)
#pragma unroll
      for (int n = 0; n < 4; n++)
#pragma unroll
        for (int q = 0; q < 4; q++) {
          int row = rowBase + wr * 64 + m * 16 + 4 * g + q;
          int col = colBase + wc * 64 + n * 16 + r;
          float v = acc[m][n][q] + bias[col];
          v = 0.5f * v * (1.0f + erff(v * 0.70710678118654752f));
          Cf[(long)row * N + col] = v;
        }
  }
}

// ------- flash attention: 8-wave, swapped-operand, shift-free softmax ----
// QBLK=256 (8 waves x 32 q-rows), KBLK=64. 3-buffer/1-barrier counted-vmcnt
// pipeline; vmcnt(2). grid 512, XCD-swizzled. Logits base-2: p = 2^st.
// NEW: softmax denominator via ones-row PV MFMA -- ldn = mfma32(ones, P)
// accumulates sum_k P[q][k] in every output row (lane's q = col), replacing
// the 31-add VALU tree + cross-half shfl. Denominator sums the SAME
// bf16-rounded P as the numerator (more consistent normalization).
__global__ __launch_bounds__(512) void attn_fwd4(
    const bf16* __restrict__ Q, const bf16* __restrict__ K,
    const bf16* __restrict__ Vt, const float* __restrict__ mbias,
    const uint* __restrict__ cleanw, bf16* __restrict__ ctx) {
  __shared__ bf16 Ks[3][64 * 64];
  __shared__ bf16 Vs[3][64 * 64];
  bf16* Ks0 = &Ks[0][0];
  bf16* Vs0 = &Vs[0][0];
  const int tid = threadIdx.x;
  const int lane = tid & 63, wv = tid >> 6;
  const int ql = lane & 31, hi = lane >> 5;
  const int g = blockIdx.x;
  const int gx = (g & 63) >> 3;
  const int bh = ((g >> 6) << 3) | (g & 7);
  const int b = bh >> 4, h = bh & 15;
  const int q0 = gx * 256 + wv * 32;

  const bf16* Qp = Q + ((long)(b * NS + q0 + ql)) * ND + h * NHD;
  const bf16* Kp = K + ((long)b * NS) * ND + h * NHD;
  const bf16* Vp = Vt + (long)bh * NHD * NS;
  const float* mbp = mbias + b * NS;
  const uint cw = cleanw[b];

  bf16x8 qf[4];
#pragma unroll
  for (int cd = 0; cd < 4; cd++)
    qf[cd] = *(const bf16x8*)(Qp + cd * 16 + hi * 8);

  bf16x8 ones;
#pragma unroll
  for (int i = 0; i < 8; i++) ones[i] = (bf16)1.0f;

  f32x16 o[2] = {};
  f32x16 ldn = {};

  const int Lrow = wv * 8 + (lane >> 3);
  const int scb = ((lane & 7) * 16) ^ ((Lrow & 7) << 4);
  const bf16* kS = Kp + (long)Lrow * ND + (scb >> 1);
  const bf16* vS = Vp + (long)Lrow * NS + (scb >> 1);

#define ASTAGE(bi, sv)                                        \
  do {                                                        \
    gload_lds16(kS + (long)(sv) * ND, Ks0 + (bi) * 4096 + wv * 512); \
    gload_lds16(vS + (sv), Vs0 + (bi) * 4096 + wv * 512);     \
  } while (0)

  const int swz = (ql & 7) << 4;

  ASTAGE(0, 0);
  int cur = 0, nxt = 1;

  for (int s0 = 0; s0 < NS; s0 += 64) {
    if (s0 + 64 < NS) {
      ASTAGE(nxt, s0 + 64);
      asm volatile("s_waitcnt vmcnt(2)" ::: "memory");
    } else {
      asm volatile("s_waitcnt vmcnt(0)" ::: "memory");
    }
    BARRIER();
    __builtin_amdgcn_sched_barrier(0);
    const char* KsB = (const char*)(Ks0 + cur * 4096);
    const char* VsB = (const char*)(Vs0 + cur * 4096);

    f32x16 st0 = {}, st1 = {};
    __builtin_amdgcn_s_setprio(1);
#pragma unroll
    for (int cd = 0; cd < 4; cd++) {
      bf16x8 kf0 = *(const bf16x8*)(KsB + ql * 128 + ((cd * 32 + hi * 16) ^ swz));
      st0 = mfma32(kf0, qf[cd], st0);
      bf16x8 kf1 = *(const bf16x8*)(KsB + (32 + ql) * 128 + ((cd * 32 + hi * 16) ^ swz));
      st1 = mfma32(kf1, qf[cd], st1);
    }
    __builtin_amdgcn_s_setprio(0);

    if (!((cw >> (s0 >> 6)) & 1)) {
#pragma unroll
      for (int t = 0; t < 4; t++) {
        float4 m0 = *(const float4*)(mbp + s0 + t * 8 + hi * 4);
        st0[4 * t + 0] += m0.x;
        st0[4 * t + 1] += m0.y;
        st0[4 * t + 2] += m0.z;
        st0[4 * t + 3] += m0.w;
        float4 m1 = *(const float4*)(mbp + s0 + 32 + t * 8 + hi * 4);
        st1[4 * t + 0] += m1.x;
        st1[4 * t + 1] += m1.y;
        st1[4 * t + 2] += m1.z;
        st1[4 * t + 3] += m1.w;
      }
    }

    // ---- shift-free softmax: p = 2^st ----
#pragma unroll
    for (int i = 0; i < 16; i++) {
      st0[i] = expv(st0[i]);
      st1[i] = expv(st1[i]);
    }

    // ---- P -> bf16 B-fragments (T12) ----
    union {
      uint u[16];
      bf16x8 f[4];
    } pw;
    {
      uint c0 = cvtpk(st0[0], st0[1]), c1 = cvtpk(st0[4], st0[5]);
      swap32u(c0, c1);
      uint d0 = cvtpk(st0[2], st0[3]), d1 = cvtpk(st0[6], st0[7]);
      swap32u(d0, d1);
      pw.u[0] = c0; pw.u[1] = d0; pw.u[2] = c1; pw.u[3] = d1;
      uint e0 = cvtpk(st0[8], st0[9]), e1 = cvtpk(st0[12], st0[13]);
      swap32u(e0, e1);
      uint f0 = cvtpk(st0[10], st0[11]), f1 = cvtpk(st0[14], st0[15]);
      swap32u(f0, f1);
      pw.u[4] = e0; pw.u[5] = f0; pw.u[6] = e1; pw.u[7] = f1;
    }
    {
      uint c0 = cvtpk(st1[0], st1[1]), c1 = cvtpk(st1[4], st1[5]);
      swap32u(c0, c1);
      uint d0 = cvtpk(st1[2], st1[3]), d1 = cvtpk(st1[6], st1[7]);
      swap32u(d0, d1);
      pw.u[8] = c0; pw.u[9] = d0; pw.u[10] = c1; pw.u[11] = d1;
      uint e0 = cvtpk(st1[8], st1[9]), e1 = cvtpk(st1[12], st1[13]);
      swap32u(e0, e1);
      uint f0 = cvtpk(st1[10], st1[11]), f1 = cvtpk(st1[14], st1[15]);
      swap32u(f0, f1);
      pw.u[12] = e0; pw.u[13] = f0; pw.u[14] = e1; pw.u[15] = f1;
    }

    // ---- O^T += V^T P^T ; denominator += ones^T P^T ----
    __builtin_amdgcn_s_setprio(1);
#pragma unroll
    for (int dt = 0; dt < 2; dt++) {
#pragma unroll
      for (int ck = 0; ck < 4; ck++) {
        bf16x8 vf = *(const bf16x8*)(VsB + (dt * 32 + ql) * 128 +
                                     ((ck * 32 + hi * 16) ^ swz));
        o[dt] = mfma32(vf, pw.f[ck], o[dt]);
      }
    }
#pragma unroll
    for (int ck = 0; ck < 4; ck++) ldn = mfma32(ones, pw.f[ck], ldn);
    __builtin_amdgcn_s_setprio(0);
    cur = nxt;
    nxt = (nxt == 2) ? 0 : nxt + 1;
  }
#undef ASTAGE

  const float invL = 1.0f / ldn[0];  // every ldn row = full sum over k
  bf16* op = ctx + ((long)(b * NS + q0 + ql)) * ND + h * NHD;
#pragma unroll
  for (int dt = 0; dt < 2; dt++) {
#pragma unroll
    for (int t = 0; t < 4; t++) {
      bf16x4 pk;
#pragma unroll
      for (int i = 0; i < 4; i++) pk[i] = (bf16)(o[dt][t * 4 + i] * invL);
      *(bf16x4*)(op + dt * 32 + t * 8 + hi * 4) = pk;
    }
  }
}

extern "C" void kernel_launch(void* const* d_in, const int* in_sizes, int n_in,
                              void* d_out, int out_size, void* d_ws, size_t ws_size,
                              hipStream_t stream) {
  const float* value = (const float*)d_in[0];
  const float* key_t = (const float*)d_in[1];
  const float* query = (const float*)d_in[2];
  const int* mask = (const int*)d_in[3];
  const float* W_q = (const float*)d_in[4];
  const float* W_k = (const float*)d_in[5];
  const float* W_v = (const float*)d_in[6];
  const float* W_o = (const float*)d_in[7];
  const float* b_o = (const float*)d_in[8];
  float* out = (float*)d_out;

  char* ws = (char*)d_ws;
  bf16* Axb = (bf16*)(ws + 0);               // 16MB A-bf16 staging; later ctx
  bf16* ctx = (bf16*)(ws + 0);               // (attn output; Axb dead by then)
  bf16* wb = (bf16*)(ws + (16UL << 20));     // 8MB: wq, wk, wv, wo
  bf16* Qb = (bf16*)(ws + (24UL << 20));     // 16MB
  bf16* Kb = (bf16*)(ws + (40UL << 20));     // 16MB
  bf16* Vtb = (bf16*)(ws + (56UL << 20));    // 16MB (pre-transposed V)
  float* mbias = (float*)(ws + (72UL << 20));
  uint* cleanwd = (uint*)(ws + (72UL << 20) + 32768);

  const int nX4 = (NB * NS * ND) / 4;  // 2M float4
  const int nW4 = (ND * ND) / 4;
  // HD^-0.5 * log2(e) folded into W_q -> logits in base-2 units
  const float hscale = 0.125f * 1.44269504088896f;

  prep<<<4129, 256, 0, stream>>>((const float4*)W_q, (const float4*)W_k,
                                 (const float4*)W_v, (const float4*)W_o,
                                 (bf16x4*)wb, hscale, nW4,
                                 mask, mbias, cleanwd, NB * NS);
  bf16* wqb = wb;
  bf16* wkb = wb + 1L * ND * ND;
  bf16* wvb = wb + 2L * ND * ND;
  bf16* wob = wb + 3L * ND * ND;

  const int ggrid = ((NB * NS) / 128) * (ND / 128);  // 64 * 8 = 512

  cvt_bf16<<<nX4 / 256, 256, 0, stream>>>((const float4*)query, (bf16x4*)Axb, 1.0f, nX4);
  gemm8<0><<<ggrid, 256, 0, stream>>>(Axb, wqb, Qb, nullptr, nullptr, NB * NS, ND, ND);

  cvt_bf16<<<nX4 / 256, 256, 0, stream>>>((const float4*)key_t, (bf16x4*)Axb, 1.0f, nX4);
  gemm8<0><<<ggrid, 256, 0, stream>>>(Axb, wkb, Kb, nullptr, nullptr, NB * NS, ND, ND);

  cvt_bf16<<<nX4 / 256, 256, 0, stream>>>((const float4*)value, (bf16x4*)Axb, 1.0f, nX4);
  gemm8<1><<<ggrid, 256, 0, stream>>>(Axb, wvb, Vtb, nullptr, nullptr, NB * NS, ND, ND);

  attn_fwd4<<<512, 512, 0, stream>>>(Qb, Kb, Vtb, mbias, cleanwd, ctx);

  gemm8<2><<<ggrid, 256, 0, stream>>>(ctx, wob, nullptr, out, b_o, NB * NS, ND, ND);
}